// Round 9
// baseline (125.468 us; speedup 1.0000x reference)
//
#include <hip/hip_runtime.h>

// GCN forward, f32. aggregate(x)@W1 == aggregate(x@W1); CSR build via
// LDS-local counting sort (no memory-side atomics); GEMM with LDS-staged W1.
// Pipeline:
//  K1 k_hist_lds : 64 chunks x 4 node-passes, packed LDS histogram -> part[]
//  K2 k_merge    : sum partials -> cnt_out/cnt_in; colpref[b][v] (ushort)
//  K3 k_scan_block / K4 k_scan_bsum : exclusive scan of cnt_in
//  K5 k_finalize : row_start; meta[v]=(start,cnt_in,cnt_out,0)
//  K6 k_bin_lds  : LDS cursor = start+colpref; col2[p]=(src, norm_src[src])
//  K7 k_gemm     : y = x @ W1   (8 rows/wave; W1 in LDS, col read amortized 8x)
//  K8 k_node     : per-node gather of y -> +b1, relu, dot W2 -> zs
//  K9 k_out      : layer-2 scalar gather -> out
// y overlays part (dead after k_merge); zs overlays cnt_in (dead after K5).

constexpr int D = 64;
constexpr int NODE_TILE = 12800;   // LDS counters per pass (50 KB)
constexpr int NCHUNK = 64;         // edge chunks
constexpr int HTH = 1024;          // threads for hist/bin blocks

__device__ __forceinline__ int rl_i(int v, int l) { return __builtin_amdgcn_readlane(v, l); }
__device__ __forceinline__ float rl_f(float v, int l) {
    return __builtin_bit_cast(float, __builtin_amdgcn_readlane(__builtin_bit_cast(int, v), l));
}

// packed LDS histogram: low 16 bits = out-degree (src), high 16 = in-degree (dst)
__global__ void __launch_bounds__(HTH) k_hist_lds(
        const int* __restrict__ src, const int* __restrict__ dst,
        unsigned int* __restrict__ part, int e, int ce) {
    __shared__ unsigned int h[NODE_TILE];
    int b = blockIdx.x;
    int v0 = blockIdx.y * NODE_TILE;
    for (int i = threadIdx.x; i < NODE_TILE; i += HTH) h[i] = 0u;
    __syncthreads();
    int lo = b * ce, hi = min(lo + ce, e);
    for (int i = lo + threadIdx.x; i < hi; i += HTH) {
        unsigned int us = (unsigned int)(src[i] - v0);
        if (us < (unsigned int)NODE_TILE) atomicAdd(&h[us], 1u);
        unsigned int ud = (unsigned int)(dst[i] - v0);
        if (ud < (unsigned int)NODE_TILE) atomicAdd(&h[ud], 0x10000u);
    }
    __syncthreads();
    unsigned int* p = part + ((size_t)blockIdx.y * NCHUNK + b) * NODE_TILE;
    for (int i = threadIdx.x; i < NODE_TILE; i += HTH) p[i] = h[i];
}

// per node: sum 64 partials -> counts; exclusive prefix of in-counts -> colpref
__global__ void k_merge(const unsigned int* __restrict__ part,
                        unsigned short* __restrict__ colpref,
                        int* __restrict__ cnt_out, int* __restrict__ cnt_in, int n) {
    int v = blockIdx.x * blockDim.x + threadIdx.x;
    if (v >= n) return;
    int pass = v / NODE_TILE;
    int vl = v - pass * NODE_TILE;
    const unsigned int* p = part + (size_t)pass * NCHUNK * NODE_TILE + vl;
    unsigned int tot = 0, run_in = 0;
    for (int b = 0; b < NCHUNK; ++b) {
        colpref[(size_t)b * n + v] = (unsigned short)run_in;
        unsigned int t = p[(size_t)b * NODE_TILE];
        tot += t;
        run_in += t >> 16;
    }
    cnt_out[v] = (int)(tot & 0xFFFFu);
    cnt_in[v] = (int)(tot >> 16);
}

__global__ void k_scan_block(const int* __restrict__ cnt_in, int* __restrict__ cursor,
                             int* __restrict__ bsum, int n) {
    __shared__ int s[256];
    int tid = threadIdx.x;
    int i = blockIdx.x * 256 + tid;
    int v = (i < n) ? cnt_in[i] : 0;
    s[tid] = v;
    __syncthreads();
#pragma unroll
    for (int off = 1; off < 256; off <<= 1) {
        int t = (tid >= off) ? s[tid - off] : 0;
        __syncthreads();
        s[tid] += t;
        __syncthreads();
    }
    if (i < n) cursor[i] = s[tid] - v;
    if (tid == 255) bsum[blockIdx.x] = s[255];
}

__global__ void k_scan_bsum(int* __restrict__ bsum, int nb) {
    __shared__ int s[256];
    __shared__ int carry;
    int tid = threadIdx.x;
    if (tid == 0) carry = 0;
    __syncthreads();
    for (int start = 0; start < nb; start += 256) {
        int i = start + tid;
        int v = (i < nb) ? bsum[i] : 0;
        s[tid] = v;
        __syncthreads();
#pragma unroll
        for (int off = 1; off < 256; off <<= 1) {
            int t = (tid >= off) ? s[tid - off] : 0;
            __syncthreads();
            s[tid] += t;
            __syncthreads();
        }
        if (i < nb) bsum[i] = s[tid] - v + carry;
        __syncthreads();
        if (tid == 0) carry += s[255];
        __syncthreads();
    }
}

__global__ void k_finalize(const int* __restrict__ cnt_out, const int* __restrict__ cnt_in,
                           const int* __restrict__ bsum,
                           int* __restrict__ cursor, int4* __restrict__ meta, int n) {
    int i = blockIdx.x * blockDim.x + threadIdx.x;
    if (i >= n) return;
    int start = cursor[i] + bsum[i >> 8];
    cursor[i] = start;
    meta[i] = make_int4(start, cnt_in[i], cnt_out[i], 0);
}

// bin via LDS cursor (fast LDS atomics); only col2 store goes to memory
__global__ void __launch_bounds__(HTH) k_bin_lds(
        const int* __restrict__ src, const int* __restrict__ dst,
        const int* __restrict__ start, const unsigned short* __restrict__ colpref,
        const int* __restrict__ cnt_out,
        int2* __restrict__ col2, int e, int n, int ce) {
    __shared__ int cur[NODE_TILE];
    int b = blockIdx.x;
    int v0 = blockIdx.y * NODE_TILE;
    int vcnt = min(NODE_TILE, n - v0);
    for (int i = threadIdx.x; i < vcnt; i += HTH)
        cur[i] = start[v0 + i] + (int)colpref[(size_t)b * n + v0 + i];
    __syncthreads();
    int lo = b * ce, hi = min(lo + ce, e);
    for (int i = lo + threadIdx.x; i < hi; i += HTH) {
        int d = dst[i];
        unsigned int ud = (unsigned int)(d - v0);
        if (ud < (unsigned int)NODE_TILE) {
            int s = src[i];
            int p = atomicAdd(&cur[ud], 1);
            float w = rsqrtf((float)(cnt_out[s] + 1));  // norm_src[s]
            col2[p] = make_int2(s, __builtin_bit_cast(int, w));
        }
    }
}

// y = x @ W1: one wave handles 8 rows; lane = output column.
// W1 staged in LDS; W1 column read once per k, shared by 8 rows (8x amortized).
__global__ void __launch_bounds__(256) k_gemm(
        const float* __restrict__ x, const float* __restrict__ W1,
        float* __restrict__ y, int n) {
    __shared__ float sW1[D * D];
    int tid = threadIdx.x;
    for (int i = tid; i < D * D; i += 256) sW1[i] = W1[i];
    __syncthreads();

    int wave = tid >> 6;
    int lane = tid & 63;
    int r0 = (blockIdx.x * 4 + wave) * 8;
    if (r0 >= n) return;

    float xr[8], acc[8];
#pragma unroll
    for (int i = 0; i < 8; ++i) {
        int r = r0 + i;
        xr[i] = (r < n) ? x[(size_t)r * D + lane] : 0.0f;
        acc[i] = 0.0f;
    }
#pragma unroll
    for (int k = 0; k < D; ++k) {
        float wk = sW1[k * D + lane];   // ds_read, 2-way alias = free
#pragma unroll
        for (int i = 0; i < 8; ++i)
            acc[i] = fmaf(rl_f(xr[i], k), wk, acc[i]);
    }
#pragma unroll
    for (int i = 0; i < 8; ++i) {
        int r = r0 + i;
        if (r < n) y[(size_t)r * D + lane] = acc[i];
    }
}

// one wave per node (grid-stride); all loads coalesced
__global__ void __launch_bounds__(256) k_node(
        const float* __restrict__ y, const int4* __restrict__ meta,
        const int2* __restrict__ col2,
        const float* __restrict__ b1, const float* __restrict__ W2,
        float* __restrict__ zs, int n) {
    int tid = threadIdx.x;
    int wave = tid >> 6;
    int lane = tid & 63;
    float b1v = b1[lane];
    float w2v = W2[lane];

    int nwaves = gridDim.x * 4;
    int node = blockIdx.x * 4 + wave;
    if (node >= n) return;
    int4 mt = meta[node];

    while (true) {
        int nxt = node + nwaves;
        int4 mt_nx = make_int4(0, 0, 0, 0);
        if (nxt < n) mt_nx = meta[nxt];          // prefetch next node's meta

        int base = mt.x;
        int cnt = mt.y;
        float nd = rsqrtf((float)(mt.y + 1));    // norm_dst
        float ns = rsqrtf((float)(mt.z + 1));    // norm_src

        float a0 = ns * y[(size_t)node * D + lane];  // self loop
        float a1 = 0.0f, a2 = 0.0f, a3 = 0.0f;

        for (int b0 = 0; b0 < cnt; b0 += 64) {
            int m = cnt - b0; if (m > 64) m = 64;
            int2 cw = (lane < m) ? col2[base + b0 + lane] : make_int2(0, 0);
            int idx = cw.x;
            float w = __builtin_bit_cast(float, cw.y);
            int j = 0;
            for (; j + 8 <= m; j += 8) {
                int s0 = rl_i(idx, j + 0), s1 = rl_i(idx, j + 1);
                int s2 = rl_i(idx, j + 2), s3 = rl_i(idx, j + 3);
                int s4 = rl_i(idx, j + 4), s5 = rl_i(idx, j + 5);
                int s6 = rl_i(idx, j + 6), s7 = rl_i(idx, j + 7);
                float x0 = y[(size_t)s0 * D + lane];
                float x1 = y[(size_t)s1 * D + lane];
                float x2 = y[(size_t)s2 * D + lane];
                float x3 = y[(size_t)s3 * D + lane];
                float x4 = y[(size_t)s4 * D + lane];
                float x5 = y[(size_t)s5 * D + lane];
                float x6 = y[(size_t)s6 * D + lane];
                float x7 = y[(size_t)s7 * D + lane];
                a0 = fmaf(rl_f(w, j + 0), x0, a0);
                a1 = fmaf(rl_f(w, j + 1), x1, a1);
                a2 = fmaf(rl_f(w, j + 2), x2, a2);
                a3 = fmaf(rl_f(w, j + 3), x3, a3);
                a0 = fmaf(rl_f(w, j + 4), x4, a0);
                a1 = fmaf(rl_f(w, j + 5), x5, a1);
                a2 = fmaf(rl_f(w, j + 6), x6, a2);
                a3 = fmaf(rl_f(w, j + 7), x7, a3);
            }
            for (; j < m; ++j)
                a0 = fmaf(rl_f(w, j), y[(size_t)rl_i(idx, j) * D + lane], a0);
        }

        float h = fmaxf(((a0 + a1) + (a2 + a3)) * nd + b1v, 0.0f);
        float zp = h * w2v;
#pragma unroll
        for (int off = 32; off > 0; off >>= 1) zp += __shfl_down(zp, off);
        if (lane == 0) zs[node] = zp * ns;       // pre-scaled for layer 2

        if (nxt >= n) break;
        node = nxt;
        mt = mt_nx;
    }
}

// layer-2 gather: 8 lanes per node
__global__ void k_out(const float* __restrict__ zs,
                      const int4* __restrict__ meta, const int2* __restrict__ col2,
                      const float* __restrict__ b2,
                      float* __restrict__ out, int n) {
    int g = blockIdx.x * blockDim.x + threadIdx.x;
    int node = g >> 3;
    int sub = g & 7;
    if (node >= n) return;
    int4 mt = meta[node];
    int base = mt.x;
    int c = mt.y;
    float s = (sub == 0) ? zs[node] : 0.0f;   // self loop (zs pre-scaled)
    for (int j = sub; j < c; j += 8) s += zs[col2[base + j].x];
    s += __shfl_xor(s, 1);
    s += __shfl_xor(s, 2);
    s += __shfl_xor(s, 4);
    if (sub == 0) {
        float nd = rsqrtf((float)(mt.y + 1));
        out[node] = nd * s + b2[0];
    }
}

extern "C" void kernel_launch(void* const* d_in, const int* in_sizes, int n_in,
                              void* d_out, int out_size, void* d_ws, size_t ws_size,
                              hipStream_t stream) {
    const float* x  = (const float*)d_in[0];
    const int*   ei = (const int*)d_in[1];
    const float* W1 = (const float*)d_in[2];
    const float* b1 = (const float*)d_in[3];
    const float* W2 = (const float*)d_in[4];
    const float* b2 = (const float*)d_in[5];
    float* out = (float*)d_out;

    const int n = in_sizes[0] / D;   // 50000
    const int e = in_sizes[1] / 2;   // 800000
    const int* src = ei;
    const int* dst = ei + e;

    const int nb = (n + 255) / 256;
    const int npass = (n + NODE_TILE - 1) / NODE_TILE;      // 4
    const int ce = (e + NCHUNK - 1) / NCHUNK;               // 12500

    // workspace layout
    char* ws = (char*)d_ws;
    int*   cnt_out = (int*)ws;   ws += sizeof(int) * (size_t)n;
    int*   cnt_in  = (int*)ws;   ws += sizeof(int) * (size_t)n;   // zs overlays after finalize
    int*   cursor  = (int*)ws;   ws += sizeof(int) * (size_t)n;
    int*   bsum    = (int*)ws;   ws += sizeof(int) * (size_t)((nb + 255) & ~255);
    int4*  meta    = (int4*)ws;  ws += sizeof(int4) * (size_t)n;
    unsigned short* colpref = (unsigned short*)ws;
    ws += sizeof(unsigned short) * (size_t)NCHUNK * n;
    int2*  col2    = (int2*)ws;  ws += sizeof(int2) * (size_t)e;
    size_t part_bytes = sizeof(unsigned int) * (size_t)npass * NCHUNK * NODE_TILE;
    size_t y_bytes    = sizeof(float) * (size_t)n * D;
    unsigned int* part = (unsigned int*)ws;
    float* y = (float*)ws;       // y overlays part (part dead after k_merge)
    ws += (part_bytes > y_bytes ? part_bytes : y_bytes);
    float* zs = (float*)cnt_in;  // cnt_in dead after k_finalize

    const int B = 256;

    k_hist_lds<<<dim3(NCHUNK, npass), HTH, 0, stream>>>(src, dst, part, e, ce);
    k_merge<<<(n + B - 1) / B, B, 0, stream>>>(part, colpref, cnt_out, cnt_in, n);
    k_scan_block<<<nb, 256, 0, stream>>>(cnt_in, cursor, bsum, n);
    k_scan_bsum<<<1, 256, 0, stream>>>(bsum, nb);
    k_finalize<<<(n + B - 1) / B, B, 0, stream>>>(cnt_out, cnt_in, bsum, cursor, meta, n);
    k_bin_lds<<<dim3(NCHUNK, npass), HTH, 0, stream>>>(src, dst, cursor, colpref,
                                                       cnt_out, col2, e, n, ce);
    k_gemm<<<(n + 31) / 32, B, 0, stream>>>(x, W1, y, n);
    k_node<<<2048, B, 0, stream>>>(y, meta, col2, b1, W2, zs, n);
    k_out<<<((size_t)n * 8 + B - 1) / B, B, 0, stream>>>(zs, meta, col2, b2, out, n);
}

// Round 10
// 113.880 us; speedup vs baseline: 1.1018x; 1.1018x over previous
//
#include <hip/hip_runtime.h>

// GCN forward, f32. aggregate(x)@W1 == aggregate(x@W1); CSR build via
// LDS-local counting sort; GEMM with x in SGPRs (s_load) + W1 in LDS.
// Pipeline:
//  K1 k_hist_lds : 64 chunks x 4 node-passes, packed LDS histogram -> part[]
//  K2 k_merge    : sum partials -> cnt_out/cnt_in; colpref[b][v] (ushort)
//  K3 k_scan_block / K4 k_scan_bsum : exclusive scan of cnt_in
//  K5 k_finalize : row_start; meta[v]=(start,cnt_in,cnt_out,0)
//  K6 k_bin_lds  : LDS cursor = start+colpref; col2[p]=(src, norm_src[src])
//  K7 k_gemm     : y = x @ W1 (8 rows/wave; x rows wave-uniform -> s_load to
//                  SGPRs, FMA with SGPR src0; W1 col via LDS; NO readlane)
//  K8 k_node     : per-node gather of y -> +b1, relu, dot W2 -> zs
//  K9 k_out      : layer-2 scalar gather -> out
// y overlays part (dead after k_merge); zs overlays cnt_in (dead after K5).

constexpr int D = 64;
constexpr int NODE_TILE = 12800;   // LDS counters per pass (50 KB)
constexpr int NCHUNK = 64;         // edge chunks
constexpr int HTH = 1024;          // threads for hist/bin blocks

typedef float f32x8 __attribute__((ext_vector_type(8)));

__device__ __forceinline__ int rl_i(int v, int l) { return __builtin_amdgcn_readlane(v, l); }
__device__ __forceinline__ float rl_f(float v, int l) {
    return __builtin_bit_cast(float, __builtin_amdgcn_readlane(__builtin_bit_cast(int, v), l));
}

// packed LDS histogram: low 16 bits = out-degree (src), high 16 = in-degree (dst)
__global__ void __launch_bounds__(HTH) k_hist_lds(
        const int* __restrict__ src, const int* __restrict__ dst,
        unsigned int* __restrict__ part, int e, int ce) {
    __shared__ unsigned int h[NODE_TILE];
    int b = blockIdx.x;
    int v0 = blockIdx.y * NODE_TILE;
    for (int i = threadIdx.x; i < NODE_TILE; i += HTH) h[i] = 0u;
    __syncthreads();
    int lo = b * ce, hi = min(lo + ce, e);
    for (int i = lo + threadIdx.x; i < hi; i += HTH) {
        unsigned int us = (unsigned int)(src[i] - v0);
        if (us < (unsigned int)NODE_TILE) atomicAdd(&h[us], 1u);
        unsigned int ud = (unsigned int)(dst[i] - v0);
        if (ud < (unsigned int)NODE_TILE) atomicAdd(&h[ud], 0x10000u);
    }
    __syncthreads();
    unsigned int* p = part + ((size_t)blockIdx.y * NCHUNK + b) * NODE_TILE;
    for (int i = threadIdx.x; i < NODE_TILE; i += HTH) p[i] = h[i];
}

// per node: sum 64 partials -> counts; exclusive prefix of in-counts -> colpref
__global__ void k_merge(const unsigned int* __restrict__ part,
                        unsigned short* __restrict__ colpref,
                        int* __restrict__ cnt_out, int* __restrict__ cnt_in, int n) {
    int v = blockIdx.x * blockDim.x + threadIdx.x;
    if (v >= n) return;
    int pass = v / NODE_TILE;
    int vl = v - pass * NODE_TILE;
    const unsigned int* p = part + (size_t)pass * NCHUNK * NODE_TILE + vl;
    unsigned int tot = 0, run_in = 0;
    for (int b = 0; b < NCHUNK; ++b) {
        colpref[(size_t)b * n + v] = (unsigned short)run_in;
        unsigned int t = p[(size_t)b * NODE_TILE];
        tot += t;
        run_in += t >> 16;
    }
    cnt_out[v] = (int)(tot & 0xFFFFu);
    cnt_in[v] = (int)(tot >> 16);
}

__global__ void k_scan_block(const int* __restrict__ cnt_in, int* __restrict__ cursor,
                             int* __restrict__ bsum, int n) {
    __shared__ int s[256];
    int tid = threadIdx.x;
    int i = blockIdx.x * 256 + tid;
    int v = (i < n) ? cnt_in[i] : 0;
    s[tid] = v;
    __syncthreads();
#pragma unroll
    for (int off = 1; off < 256; off <<= 1) {
        int t = (tid >= off) ? s[tid - off] : 0;
        __syncthreads();
        s[tid] += t;
        __syncthreads();
    }
    if (i < n) cursor[i] = s[tid] - v;
    if (tid == 255) bsum[blockIdx.x] = s[255];
}

__global__ void k_scan_bsum(int* __restrict__ bsum, int nb) {
    __shared__ int s[256];
    __shared__ int carry;
    int tid = threadIdx.x;
    if (tid == 0) carry = 0;
    __syncthreads();
    for (int start = 0; start < nb; start += 256) {
        int i = start + tid;
        int v = (i < nb) ? bsum[i] : 0;
        s[tid] = v;
        __syncthreads();
#pragma unroll
        for (int off = 1; off < 256; off <<= 1) {
            int t = (tid >= off) ? s[tid - off] : 0;
            __syncthreads();
            s[tid] += t;
            __syncthreads();
        }
        if (i < nb) bsum[i] = s[tid] - v + carry;
        __syncthreads();
        if (tid == 0) carry += s[255];
        __syncthreads();
    }
}

__global__ void k_finalize(const int* __restrict__ cnt_out, const int* __restrict__ cnt_in,
                           const int* __restrict__ bsum,
                           int* __restrict__ cursor, int4* __restrict__ meta, int n) {
    int i = blockIdx.x * blockDim.x + threadIdx.x;
    if (i >= n) return;
    int start = cursor[i] + bsum[i >> 8];
    cursor[i] = start;
    meta[i] = make_int4(start, cnt_in[i], cnt_out[i], 0);
}

// bin via LDS cursor (fast LDS atomics); only col2 store goes to memory
__global__ void __launch_bounds__(HTH) k_bin_lds(
        const int* __restrict__ src, const int* __restrict__ dst,
        const int* __restrict__ start, const unsigned short* __restrict__ colpref,
        const int* __restrict__ cnt_out,
        int2* __restrict__ col2, int e, int n, int ce) {
    __shared__ int cur[NODE_TILE];
    int b = blockIdx.x;
    int v0 = blockIdx.y * NODE_TILE;
    int vcnt = min(NODE_TILE, n - v0);
    for (int i = threadIdx.x; i < vcnt; i += HTH)
        cur[i] = start[v0 + i] + (int)colpref[(size_t)b * n + v0 + i];
    __syncthreads();
    int lo = b * ce, hi = min(lo + ce, e);
    for (int i = lo + threadIdx.x; i < hi; i += HTH) {
        int d = dst[i];
        unsigned int ud = (unsigned int)(d - v0);
        if (ud < (unsigned int)NODE_TILE) {
            int s = src[i];
            int p = atomicAdd(&cur[ud], 1);
            float w = rsqrtf((float)(cnt_out[s] + 1));  // norm_src[s]
            col2[p] = make_int2(s, __builtin_bit_cast(int, w));
        }
    }
}

// y = x @ W1: one wave handles 8 rows; lane = output column.
// x rows are wave-uniform -> s_load 8x8 subtile into 64 SGPRs per k-tile;
// inner FMA: v_fma(acc, s_x, v_wk) -- no readlane, no per-element broadcast.
__global__ void __launch_bounds__(256) k_gemm(
        const float* __restrict__ x, const float* __restrict__ W1,
        float* __restrict__ y, int n) {
    __shared__ float sW1[D * D];
    int tid = threadIdx.x;
    for (int i = tid; i < D * D; i += 256) sW1[i] = W1[i];
    __syncthreads();

    int lane = tid & 63;
    int wv = __builtin_amdgcn_readfirstlane(tid >> 6);
    int r0 = (blockIdx.x * 4 + wv) * 8;
    if (r0 >= n) return;

    float acc[8];
#pragma unroll
    for (int i = 0; i < 8; ++i) acc[i] = 0.0f;

    if (r0 + 8 <= n) {
        const float* xw = x + (size_t)r0 * D;
#pragma unroll
        for (int kt = 0; kt < 8; ++kt) {
            const float* p = xw + kt * 8;
            f32x8 X0, X1, X2, X3, X4, X5, X6, X7;
            // 8 rows x 8 k-values -> SGPRs; self-contained wait (data-safe:
            // consumers depend on asm outputs)
            asm volatile(
                "s_load_dwordx8 %0, %8, 0x0\n\t"
                "s_load_dwordx8 %1, %8, 0x100\n\t"
                "s_load_dwordx8 %2, %8, 0x200\n\t"
                "s_load_dwordx8 %3, %8, 0x300\n\t"
                "s_load_dwordx8 %4, %8, 0x400\n\t"
                "s_load_dwordx8 %5, %8, 0x500\n\t"
                "s_load_dwordx8 %6, %8, 0x600\n\t"
                "s_load_dwordx8 %7, %8, 0x700\n\t"
                "s_waitcnt lgkmcnt(0)"
                : "=s"(X0), "=s"(X1), "=s"(X2), "=s"(X3),
                  "=s"(X4), "=s"(X5), "=s"(X6), "=s"(X7)
                : "s"(p));
#pragma unroll
            for (int j = 0; j < 8; ++j) {
                float wk = sW1[(kt * 8 + j) * D + lane];
                acc[0] = fmaf(X0[j], wk, acc[0]);
                acc[1] = fmaf(X1[j], wk, acc[1]);
                acc[2] = fmaf(X2[j], wk, acc[2]);
                acc[3] = fmaf(X3[j], wk, acc[3]);
                acc[4] = fmaf(X4[j], wk, acc[4]);
                acc[5] = fmaf(X5[j], wk, acc[5]);
                acc[6] = fmaf(X6[j], wk, acc[6]);
                acc[7] = fmaf(X7[j], wk, acc[7]);
            }
        }
#pragma unroll
        for (int i = 0; i < 8; ++i)
            y[(size_t)(r0 + i) * D + lane] = acc[i];
    } else {
        // tail (never taken for n % 8 == 0): readlane fallback
        float xr[8];
#pragma unroll
        for (int i = 0; i < 8; ++i) {
            int r = r0 + i;
            xr[i] = (r < n) ? x[(size_t)r * D + lane] : 0.0f;
        }
#pragma unroll
        for (int k = 0; k < D; ++k) {
            float wk = sW1[k * D + lane];
#pragma unroll
            for (int i = 0; i < 8; ++i)
                acc[i] = fmaf(rl_f(xr[i], k), wk, acc[i]);
        }
#pragma unroll
        for (int i = 0; i < 8; ++i) {
            int r = r0 + i;
            if (r < n) y[(size_t)r * D + lane] = acc[i];
        }
    }
}

// one wave per node (grid-stride); all loads coalesced
__global__ void __launch_bounds__(256) k_node(
        const float* __restrict__ y, const int4* __restrict__ meta,
        const int2* __restrict__ col2,
        const float* __restrict__ b1, const float* __restrict__ W2,
        float* __restrict__ zs, int n) {
    int tid = threadIdx.x;
    int wave = tid >> 6;
    int lane = tid & 63;
    float b1v = b1[lane];
    float w2v = W2[lane];

    int nwaves = gridDim.x * 4;
    int node = blockIdx.x * 4 + wave;
    if (node >= n) return;
    int4 mt = meta[node];

    while (true) {
        int nxt = node + nwaves;
        int4 mt_nx = make_int4(0, 0, 0, 0);
        if (nxt < n) mt_nx = meta[nxt];          // prefetch next node's meta

        int base = mt.x;
        int cnt = mt.y;
        float nd = rsqrtf((float)(mt.y + 1));    // norm_dst
        float ns = rsqrtf((float)(mt.z + 1));    // norm_src

        float a0 = ns * y[(size_t)node * D + lane];  // self loop
        float a1 = 0.0f, a2 = 0.0f, a3 = 0.0f;

        for (int b0 = 0; b0 < cnt; b0 += 64) {
            int m = cnt - b0; if (m > 64) m = 64;
            int2 cw = (lane < m) ? col2[base + b0 + lane] : make_int2(0, 0);
            int idx = cw.x;
            float w = __builtin_bit_cast(float, cw.y);
            int j = 0;
            for (; j + 8 <= m; j += 8) {
                int s0 = rl_i(idx, j + 0), s1 = rl_i(idx, j + 1);
                int s2 = rl_i(idx, j + 2), s3 = rl_i(idx, j + 3);
                int s4 = rl_i(idx, j + 4), s5 = rl_i(idx, j + 5);
                int s6 = rl_i(idx, j + 6), s7 = rl_i(idx, j + 7);
                float x0 = y[(size_t)s0 * D + lane];
                float x1 = y[(size_t)s1 * D + lane];
                float x2 = y[(size_t)s2 * D + lane];
                float x3 = y[(size_t)s3 * D + lane];
                float x4 = y[(size_t)s4 * D + lane];
                float x5 = y[(size_t)s5 * D + lane];
                float x6 = y[(size_t)s6 * D + lane];
                float x7 = y[(size_t)s7 * D + lane];
                a0 = fmaf(rl_f(w, j + 0), x0, a0);
                a1 = fmaf(rl_f(w, j + 1), x1, a1);
                a2 = fmaf(rl_f(w, j + 2), x2, a2);
                a3 = fmaf(rl_f(w, j + 3), x3, a3);
                a0 = fmaf(rl_f(w, j + 4), x4, a0);
                a1 = fmaf(rl_f(w, j + 5), x5, a1);
                a2 = fmaf(rl_f(w, j + 6), x6, a2);
                a3 = fmaf(rl_f(w, j + 7), x7, a3);
            }
            for (; j < m; ++j)
                a0 = fmaf(rl_f(w, j), y[(size_t)rl_i(idx, j) * D + lane], a0);
        }

        float h = fmaxf(((a0 + a1) + (a2 + a3)) * nd + b1v, 0.0f);
        float zp = h * w2v;
#pragma unroll
        for (int off = 32; off > 0; off >>= 1) zp += __shfl_down(zp, off);
        if (lane == 0) zs[node] = zp * ns;       // pre-scaled for layer 2

        if (nxt >= n) break;
        node = nxt;
        mt = mt_nx;
    }
}

// layer-2 gather: 8 lanes per node
__global__ void k_out(const float* __restrict__ zs,
                      const int4* __restrict__ meta, const int2* __restrict__ col2,
                      const float* __restrict__ b2,
                      float* __restrict__ out, int n) {
    int g = blockIdx.x * blockDim.x + threadIdx.x;
    int node = g >> 3;
    int sub = g & 7;
    if (node >= n) return;
    int4 mt = meta[node];
    int base = mt.x;
    int c = mt.y;
    float s = (sub == 0) ? zs[node] : 0.0f;   // self loop (zs pre-scaled)
    for (int j = sub; j < c; j += 8) s += zs[col2[base + j].x];
    s += __shfl_xor(s, 1);
    s += __shfl_xor(s, 2);
    s += __shfl_xor(s, 4);
    if (sub == 0) {
        float nd = rsqrtf((float)(mt.y + 1));
        out[node] = nd * s + b2[0];
    }
}

extern "C" void kernel_launch(void* const* d_in, const int* in_sizes, int n_in,
                              void* d_out, int out_size, void* d_ws, size_t ws_size,
                              hipStream_t stream) {
    const float* x  = (const float*)d_in[0];
    const int*   ei = (const int*)d_in[1];
    const float* W1 = (const float*)d_in[2];
    const float* b1 = (const float*)d_in[3];
    const float* W2 = (const float*)d_in[4];
    const float* b2 = (const float*)d_in[5];
    float* out = (float*)d_out;

    const int n = in_sizes[0] / D;   // 50000
    const int e = in_sizes[1] / 2;   // 800000
    const int* src = ei;
    const int* dst = ei + e;

    const int nb = (n + 255) / 256;
    const int npass = (n + NODE_TILE - 1) / NODE_TILE;      // 4
    const int ce = (e + NCHUNK - 1) / NCHUNK;               // 12500

    // workspace layout
    char* ws = (char*)d_ws;
    int*   cnt_out = (int*)ws;   ws += sizeof(int) * (size_t)n;
    int*   cnt_in  = (int*)ws;   ws += sizeof(int) * (size_t)n;   // zs overlays after finalize
    int*   cursor  = (int*)ws;   ws += sizeof(int) * (size_t)n;
    int*   bsum    = (int*)ws;   ws += sizeof(int) * (size_t)((nb + 255) & ~255);
    int4*  meta    = (int4*)ws;  ws += sizeof(int4) * (size_t)n;
    unsigned short* colpref = (unsigned short*)ws;
    ws += sizeof(unsigned short) * (size_t)NCHUNK * n;
    int2*  col2    = (int2*)ws;  ws += sizeof(int2) * (size_t)e;
    size_t part_bytes = sizeof(unsigned int) * (size_t)npass * NCHUNK * NODE_TILE;
    size_t y_bytes    = sizeof(float) * (size_t)n * D;
    unsigned int* part = (unsigned int*)ws;
    float* y = (float*)ws;       // y overlays part (part dead after k_merge)
    ws += (part_bytes > y_bytes ? part_bytes : y_bytes);
    float* zs = (float*)cnt_in;  // cnt_in dead after k_finalize

    const int B = 256;

    k_hist_lds<<<dim3(NCHUNK, npass), HTH, 0, stream>>>(src, dst, part, e, ce);
    k_merge<<<(n + B - 1) / B, B, 0, stream>>>(part, colpref, cnt_out, cnt_in, n);
    k_scan_block<<<nb, 256, 0, stream>>>(cnt_in, cursor, bsum, n);
    k_scan_bsum<<<1, 256, 0, stream>>>(bsum, nb);
    k_finalize<<<(n + B - 1) / B, B, 0, stream>>>(cnt_out, cnt_in, bsum, cursor, meta, n);
    k_bin_lds<<<dim3(NCHUNK, npass), HTH, 0, stream>>>(src, dst, cursor, colpref,
                                                       cnt_out, col2, e, n, ce);
    k_gemm<<<(n + 31) / 32, B, 0, stream>>>(x, W1, y, n);
    k_node<<<2048, B, 0, stream>>>(y, meta, col2, b1, W2, zs, n);
    k_out<<<((size_t)n * 8 + B - 1) / B, B, 0, stream>>>(zs, meta, col2, b2, out, n);
}

// Round 13
// 111.045 us; speedup vs baseline: 1.1299x; 1.0255x over previous
//
#include <hip/hip_runtime.h>

// GCN forward, f32. aggregate(x)@W1 == aggregate(x@W1); CSR build via
// LDS-local counting sort. y stays f32 (16-bit y aborted twice: R11/R12).
// Pipeline:
//  K1 k_hist_lds   : 64 chunks x 4 node-passes, packed LDS histogram -> part[]
//  K2 k_merge_scan : sum partials -> cnt_out/cnt_in + colpref; block-local
//                    exclusive scan of cnt_in -> cursor(partial) + bsum
//  K3 k_scan_bsum  : exclusive scan of bsum (single block)
//  K4 k_finalize   : row_start; meta[v]=(start,cnt_in,cnt_out,0)
//  K5 k_bin_lds    : LDS cursor = start+colpref; col[p] = src | cnt_out<<16
//  K6 k_gemm       : y = x @ W1 (8 rows/wave; x via s_load to SGPRs)
//  K7 k_node       : per-node gather of y -> +b1, relu, dot W2 -> zs
//  K8 k_out        : layer-2 scalar gather -> out
// y overlays part (dead after merge); zs overlays cnt_in (dead after K4).

constexpr int D = 64;
constexpr int NODE_TILE = 12800;   // LDS counters per pass (50 KB)
constexpr int NCHUNK = 64;         // edge chunks
constexpr int HTH = 1024;          // threads for hist/bin blocks

typedef float f32x8 __attribute__((ext_vector_type(8)));

__device__ __forceinline__ int rl_i(int v, int l) { return __builtin_amdgcn_readlane(v, l); }
__device__ __forceinline__ float rl_f(float v, int l) {
    return __builtin_bit_cast(float, __builtin_amdgcn_readlane(__builtin_bit_cast(int, v), l));
}

// packed LDS histogram: low 16 bits = out-degree (src), high 16 = in-degree (dst)
__global__ void __launch_bounds__(HTH) k_hist_lds(
        const int* __restrict__ src, const int* __restrict__ dst,
        unsigned int* __restrict__ part, int e, int ce) {
    __shared__ unsigned int h[NODE_TILE];
    int b = blockIdx.x;
    int v0 = blockIdx.y * NODE_TILE;
    for (int i = threadIdx.x; i < NODE_TILE; i += HTH) h[i] = 0u;
    __syncthreads();
    int lo = b * ce, hi = min(lo + ce, e);
    for (int i = lo + threadIdx.x; i < hi; i += HTH) {
        unsigned int us = (unsigned int)(src[i] - v0);
        if (us < (unsigned int)NODE_TILE) atomicAdd(&h[us], 1u);
        unsigned int ud = (unsigned int)(dst[i] - v0);
        if (ud < (unsigned int)NODE_TILE) atomicAdd(&h[ud], 0x10000u);
    }
    __syncthreads();
    unsigned int* p = part + ((size_t)blockIdx.y * NCHUNK + b) * NODE_TILE;
    for (int i = threadIdx.x; i < NODE_TILE; i += HTH) p[i] = h[i];
}

// per node: sum 64 partials -> counts + colpref; then block-local exclusive
// scan of cnt_in -> cursor(partial) + per-block sum
__global__ void k_merge_scan(const unsigned int* __restrict__ part,
                             unsigned short* __restrict__ colpref,
                             int* __restrict__ cnt_out, int* __restrict__ cnt_in,
                             int* __restrict__ cursor, int* __restrict__ bsum, int n) {
    __shared__ int s[256];
    int tid = threadIdx.x;
    int v = blockIdx.x * 256 + tid;
    int ci = 0;
    if (v < n) {
        int pass = v / NODE_TILE;
        int vl = v - pass * NODE_TILE;
        const unsigned int* p = part + (size_t)pass * NCHUNK * NODE_TILE + vl;
        unsigned int tot = 0, run_in = 0;
        for (int b = 0; b < NCHUNK; ++b) {
            colpref[(size_t)b * n + v] = (unsigned short)run_in;
            unsigned int t = p[(size_t)b * NODE_TILE];
            tot += t;
            run_in += t >> 16;
        }
        cnt_out[v] = (int)(tot & 0xFFFFu);
        ci = (int)(tot >> 16);
        cnt_in[v] = ci;
    }
    s[tid] = ci;
    __syncthreads();
#pragma unroll
    for (int off = 1; off < 256; off <<= 1) {
        int t = (tid >= off) ? s[tid - off] : 0;
        __syncthreads();
        s[tid] += t;
        __syncthreads();
    }
    if (v < n) cursor[v] = s[tid] - ci;
    if (tid == 255) bsum[blockIdx.x] = s[255];
}

__global__ void k_scan_bsum(int* __restrict__ bsum, int nb) {
    __shared__ int s[256];
    __shared__ int carry;
    int tid = threadIdx.x;
    if (tid == 0) carry = 0;
    __syncthreads();
    for (int start = 0; start < nb; start += 256) {
        int i = start + tid;
        int v = (i < nb) ? bsum[i] : 0;
        s[tid] = v;
        __syncthreads();
#pragma unroll
        for (int off = 1; off < 256; off <<= 1) {
            int t = (tid >= off) ? s[tid - off] : 0;
            __syncthreads();
            s[tid] += t;
            __syncthreads();
        }
        if (i < nb) bsum[i] = s[tid] - v + carry;
        __syncthreads();
        if (tid == 0) carry += s[255];
        __syncthreads();
    }
}

__global__ void k_finalize(const int* __restrict__ cnt_out, const int* __restrict__ cnt_in,
                           const int* __restrict__ bsum,
                           int* __restrict__ cursor, int4* __restrict__ meta, int n) {
    int i = blockIdx.x * blockDim.x + threadIdx.x;
    if (i >= n) return;
    int start = cursor[i] + bsum[i >> 8];
    cursor[i] = start;
    meta[i] = make_int4(start, cnt_in[i], cnt_out[i], 0);
}

// bin via LDS cursor; col[p] = src | cnt_out[src]<<16  (4B per edge)
__global__ void __launch_bounds__(HTH) k_bin_lds(
        const int* __restrict__ src, const int* __restrict__ dst,
        const int* __restrict__ start, const unsigned short* __restrict__ colpref,
        const int* __restrict__ cnt_out,
        unsigned int* __restrict__ col, int e, int n, int ce) {
    __shared__ int cur[NODE_TILE];
    int b = blockIdx.x;
    int v0 = blockIdx.y * NODE_TILE;
    int vcnt = min(NODE_TILE, n - v0);
    for (int i = threadIdx.x; i < vcnt; i += HTH)
        cur[i] = start[v0 + i] + (int)colpref[(size_t)b * n + v0 + i];
    __syncthreads();
    int lo = b * ce, hi = min(lo + ce, e);
    for (int i = lo + threadIdx.x; i < hi; i += HTH) {
        int d = dst[i];
        unsigned int ud = (unsigned int)(d - v0);
        if (ud < (unsigned int)NODE_TILE) {
            int s = src[i];
            int p = atomicAdd(&cur[ud], 1);
            col[p] = (unsigned int)s | ((unsigned int)cnt_out[s] << 16);
        }
    }
}

// y = x @ W1: one wave handles 8 rows; lane = output column.
// x rows wave-uniform -> s_load 8x8 subtile into SGPRs; FMA with SGPR src.
__global__ void __launch_bounds__(256) k_gemm(
        const float* __restrict__ x, const float* __restrict__ W1,
        float* __restrict__ y, int n) {
    __shared__ float sW1[D * D];
    int tid = threadIdx.x;
    for (int i = tid; i < D * D; i += 256) sW1[i] = W1[i];
    __syncthreads();

    int lane = tid & 63;
    int wv = __builtin_amdgcn_readfirstlane(tid >> 6);
    int r0 = (blockIdx.x * 4 + wv) * 8;
    if (r0 >= n) return;

    float acc[8];
#pragma unroll
    for (int i = 0; i < 8; ++i) acc[i] = 0.0f;

    if (r0 + 8 <= n) {
        const float* xw = x + (size_t)r0 * D;
#pragma unroll
        for (int kt = 0; kt < 8; ++kt) {
            const float* p = xw + kt * 8;
            f32x8 X0, X1, X2, X3, X4, X5, X6, X7;
            asm volatile(
                "s_load_dwordx8 %0, %8, 0x0\n\t"
                "s_load_dwordx8 %1, %8, 0x100\n\t"
                "s_load_dwordx8 %2, %8, 0x200\n\t"
                "s_load_dwordx8 %3, %8, 0x300\n\t"
                "s_load_dwordx8 %4, %8, 0x400\n\t"
                "s_load_dwordx8 %5, %8, 0x500\n\t"
                "s_load_dwordx8 %6, %8, 0x600\n\t"
                "s_load_dwordx8 %7, %8, 0x700\n\t"
                "s_waitcnt lgkmcnt(0)"
                : "=s"(X0), "=s"(X1), "=s"(X2), "=s"(X3),
                  "=s"(X4), "=s"(X5), "=s"(X6), "=s"(X7)
                : "s"(p));
#pragma unroll
            for (int j = 0; j < 8; ++j) {
                float wk = sW1[(kt * 8 + j) * D + lane];
                acc[0] = fmaf(X0[j], wk, acc[0]);
                acc[1] = fmaf(X1[j], wk, acc[1]);
                acc[2] = fmaf(X2[j], wk, acc[2]);
                acc[3] = fmaf(X3[j], wk, acc[3]);
                acc[4] = fmaf(X4[j], wk, acc[4]);
                acc[5] = fmaf(X5[j], wk, acc[5]);
                acc[6] = fmaf(X6[j], wk, acc[6]);
                acc[7] = fmaf(X7[j], wk, acc[7]);
            }
        }
#pragma unroll
        for (int i = 0; i < 8; ++i)
            y[(size_t)(r0 + i) * D + lane] = acc[i];
    } else {
        // tail (never taken for n % 8 == 0): readlane fallback
        float xr[8];
#pragma unroll
        for (int i = 0; i < 8; ++i) {
            int r = r0 + i;
            xr[i] = (r < n) ? x[(size_t)r * D + lane] : 0.0f;
        }
#pragma unroll
        for (int k = 0; k < D; ++k) {
            float wk = sW1[k * D + lane];
#pragma unroll
            for (int i = 0; i < 8; ++i)
                acc[i] = fmaf(rl_f(xr[i], k), wk, acc[i]);
        }
#pragma unroll
        for (int i = 0; i < 8; ++i) {
            int r = r0 + i;
            if (r < n) y[(size_t)r * D + lane] = acc[i];
        }
    }
}

// one wave per node (grid-stride); all loads coalesced; col unpacked per-lane
__global__ void __launch_bounds__(256) k_node(
        const float* __restrict__ y, const int4* __restrict__ meta,
        const unsigned int* __restrict__ col,
        const float* __restrict__ b1, const float* __restrict__ W2,
        float* __restrict__ zs, int n) {
    int tid = threadIdx.x;
    int wave = tid >> 6;
    int lane = tid & 63;
    float b1v = b1[lane];
    float w2v = W2[lane];

    int nwaves = gridDim.x * 4;
    int node = blockIdx.x * 4 + wave;
    if (node >= n) return;
    int4 mt = meta[node];

    while (true) {
        int nxt = node + nwaves;
        int4 mt_nx = make_int4(0, 0, 0, 0);
        if (nxt < n) mt_nx = meta[nxt];          // prefetch next node's meta

        int base = mt.x;
        int cnt = mt.y;
        float nd = rsqrtf((float)(mt.y + 1));    // norm_dst
        float ns = rsqrtf((float)(mt.z + 1));    // norm_src

        float a0 = ns * y[(size_t)node * D + lane];  // self loop
        float a1 = 0.0f, a2 = 0.0f, a3 = 0.0f;

        for (int b0 = 0; b0 < cnt; b0 += 64) {
            int m = cnt - b0; if (m > 64) m = 64;
            unsigned int cw = (lane < m) ? col[base + b0 + lane] : 0u;
            int idx = (int)(cw & 0xFFFFu);
            float w = rsqrtf((float)(cw >> 16) + 1.0f);  // norm_src[idx]
            int j = 0;
            for (; j + 8 <= m; j += 8) {
                int s0 = rl_i(idx, j + 0), s1 = rl_i(idx, j + 1);
                int s2 = rl_i(idx, j + 2), s3 = rl_i(idx, j + 3);
                int s4 = rl_i(idx, j + 4), s5 = rl_i(idx, j + 5);
                int s6 = rl_i(idx, j + 6), s7 = rl_i(idx, j + 7);
                float x0 = y[(size_t)s0 * D + lane];
                float x1 = y[(size_t)s1 * D + lane];
                float x2 = y[(size_t)s2 * D + lane];
                float x3 = y[(size_t)s3 * D + lane];
                float x4 = y[(size_t)s4 * D + lane];
                float x5 = y[(size_t)s5 * D + lane];
                float x6 = y[(size_t)s6 * D + lane];
                float x7 = y[(size_t)s7 * D + lane];
                a0 = fmaf(rl_f(w, j + 0), x0, a0);
                a1 = fmaf(rl_f(w, j + 1), x1, a1);
                a2 = fmaf(rl_f(w, j + 2), x2, a2);
                a3 = fmaf(rl_f(w, j + 3), x3, a3);
                a0 = fmaf(rl_f(w, j + 4), x4, a0);
                a1 = fmaf(rl_f(w, j + 5), x5, a1);
                a2 = fmaf(rl_f(w, j + 6), x6, a2);
                a3 = fmaf(rl_f(w, j + 7), x7, a3);
            }
            for (; j < m; ++j)
                a0 = fmaf(rl_f(w, j), y[(size_t)rl_i(idx, j) * D + lane], a0);
        }

        float h = fmaxf(((a0 + a1) + (a2 + a3)) * nd + b1v, 0.0f);
        float zp = h * w2v;
#pragma unroll
        for (int off = 32; off > 0; off >>= 1) zp += __shfl_down(zp, off);
        if (lane == 0) zs[node] = zp * ns;       // pre-scaled for layer 2

        if (nxt >= n) break;
        node = nxt;
        mt = mt_nx;
    }
}

// layer-2 gather: 8 lanes per node
__global__ void k_out(const float* __restrict__ zs,
                      const int4* __restrict__ meta, const unsigned int* __restrict__ col,
                      const float* __restrict__ b2,
                      float* __restrict__ out, int n) {
    int g = blockIdx.x * blockDim.x + threadIdx.x;
    int node = g >> 3;
    int sub = g & 7;
    if (node >= n) return;
    int4 mt = meta[node];
    int base = mt.x;
    int c = mt.y;
    float s = (sub == 0) ? zs[node] : 0.0f;   // self loop (zs pre-scaled)
    for (int j = sub; j < c; j += 8) s += zs[col[base + j] & 0xFFFFu];
    s += __shfl_xor(s, 1);
    s += __shfl_xor(s, 2);
    s += __shfl_xor(s, 4);
    if (sub == 0) {
        float nd = rsqrtf((float)(mt.y + 1));
        out[node] = nd * s + b2[0];
    }
}

extern "C" void kernel_launch(void* const* d_in, const int* in_sizes, int n_in,
                              void* d_out, int out_size, void* d_ws, size_t ws_size,
                              hipStream_t stream) {
    const float* x  = (const float*)d_in[0];
    const int*   ei = (const int*)d_in[1];
    const float* W1 = (const float*)d_in[2];
    const float* b1 = (const float*)d_in[3];
    const float* W2 = (const float*)d_in[4];
    const float* b2 = (const float*)d_in[5];
    float* out = (float*)d_out;

    const int n = in_sizes[0] / D;   // 50000
    const int e = in_sizes[1] / 2;   // 800000
    const int* src = ei;
    const int* dst = ei + e;

    const int nb = (n + 255) / 256;
    const int npass = (n + NODE_TILE - 1) / NODE_TILE;      // 4
    const int ce = (e + NCHUNK - 1) / NCHUNK;               // 12500

    // workspace layout
    char* ws = (char*)d_ws;
    int*   cnt_out = (int*)ws;   ws += sizeof(int) * (size_t)n;
    int*   cnt_in  = (int*)ws;   ws += sizeof(int) * (size_t)n;   // zs overlays after finalize
    int*   cursor  = (int*)ws;   ws += sizeof(int) * (size_t)n;
    int*   bsum    = (int*)ws;   ws += sizeof(int) * (size_t)((nb + 255) & ~255);
    int4*  meta    = (int4*)ws;  ws += sizeof(int4) * (size_t)n;
    unsigned short* colpref = (unsigned short*)ws;
    ws += sizeof(unsigned short) * (size_t)NCHUNK * n;
    unsigned int* col = (unsigned int*)ws;  ws += sizeof(unsigned int) * (size_t)e;
    size_t part_bytes = sizeof(unsigned int) * (size_t)npass * NCHUNK * NODE_TILE;
    size_t y_bytes    = sizeof(float) * (size_t)n * D;
    unsigned int* part = (unsigned int*)ws;
    float* y = (float*)ws;       // y overlays part (part dead after merge)
    ws += (part_bytes > y_bytes ? part_bytes : y_bytes);
    float* zs = (float*)cnt_in;  // cnt_in dead after k_finalize

    const int B = 256;

    k_hist_lds<<<dim3(NCHUNK, npass), HTH, 0, stream>>>(src, dst, part, e, ce);
    k_merge_scan<<<nb, 256, 0, stream>>>(part, colpref, cnt_out, cnt_in, cursor, bsum, n);
    k_scan_bsum<<<1, 256, 0, stream>>>(bsum, nb);
    k_finalize<<<(n + B - 1) / B, B, 0, stream>>>(cnt_out, cnt_in, bsum, cursor, meta, n);
    k_bin_lds<<<dim3(NCHUNK, npass), HTH, 0, stream>>>(src, dst, cursor, colpref,
                                                       cnt_out, col, e, n, ce);
    k_gemm<<<(n + 31) / 32, B, 0, stream>>>(x, W1, y, n);
    k_node<<<2048, B, 0, stream>>>(y, meta, col, b1, W2, zs, n);
    k_out<<<((size_t)n * 8 + B - 1) / B, B, 0, stream>>>(zs, meta, col, b2, out, n);
}

// Round 14
// 105.616 us; speedup vs baseline: 1.1880x; 1.0514x over previous
//
#include <hip/hip_runtime.h>

// GCN forward, f32. aggregate(x)@W1 == aggregate(x@W1); CSR build via
// LDS-local counting sort. y stays f32 (fp16-y aborted twice: R11/R12).
// Pipeline (6 launches):
//  K1 k_hist_gemm : fused block-partitioned kernel --
//                   blocks [0,256): packed LDS histogram -> part[]
//                   blocks [256,..): y = x @ W1 (8 rows/wave, x via s_load)
//  K2 k_merge_scan: sum partials -> cnt_out/cnt_in + colpref; block-local
//                   exclusive scan of cnt_in -> cursor(partial) + bsum
//  K3 k_scan_bsum : exclusive scan of bsum (single block)
//  K4 k_bin_lds   : LDS cursor = cursor+bsum+colpref; col[p]=src|cnt_out<<16;
//                   b==0 blocks also write meta[v]=(start,cnt_in,cnt_out,0)
//  K5 k_node      : per-node gather of y -> +b1, relu, dot W2 -> zs
//  K6 k_out       : layer-2 scalar gather -> out
// No buffer overlays (ws >= 268 MB per harness poison fill).

constexpr int D = 64;
constexpr int NODE_TILE = 12800;   // LDS counters per pass (50 KB)
constexpr int NCHUNK = 64;         // edge chunks
constexpr int HTH = 1024;          // threads for hist/bin/fused blocks

typedef float f32x8 __attribute__((ext_vector_type(8)));

__device__ __forceinline__ int rl_i(int v, int l) { return __builtin_amdgcn_readlane(v, l); }
__device__ __forceinline__ float rl_f(float v, int l) {
    return __builtin_bit_cast(float, __builtin_amdgcn_readlane(__builtin_bit_cast(int, v), l));
}

// Fused: hist blocks build packed per-chunk histograms (low16=out, high16=in);
// gemm blocks compute y = x @ W1 with x rows in SGPRs (wave-uniform s_load).
__global__ void __launch_bounds__(HTH) k_hist_gemm(
        const int* __restrict__ src, const int* __restrict__ dst,
        unsigned int* __restrict__ part, int e, int ce, int hblocks,
        const float* __restrict__ x, const float* __restrict__ W1,
        float* __restrict__ y, int n) {
    extern __shared__ char smem[];
    int tid = threadIdx.x;

    if (blockIdx.x < (unsigned)hblocks) {
        // ---- histogram part ----
        unsigned int* h = (unsigned int*)smem;
        int b = blockIdx.x & (NCHUNK - 1);
        int pass = blockIdx.x >> 6;           // log2(NCHUNK)
        int v0 = pass * NODE_TILE;
        for (int i = tid; i < NODE_TILE; i += HTH) h[i] = 0u;
        __syncthreads();
        int lo = b * ce, hi = min(lo + ce, e);
        for (int i = lo + tid; i < hi; i += HTH) {
            unsigned int us = (unsigned int)(src[i] - v0);
            if (us < (unsigned int)NODE_TILE) atomicAdd(&h[us], 1u);
            unsigned int ud = (unsigned int)(dst[i] - v0);
            if (ud < (unsigned int)NODE_TILE) atomicAdd(&h[ud], 0x10000u);
        }
        __syncthreads();
        unsigned int* p = part + ((size_t)pass * NCHUNK + b) * NODE_TILE;
        for (int i = tid; i < NODE_TILE; i += HTH) p[i] = h[i];
    } else {
        // ---- gemm part: 16 waves x 8 rows = 128 rows per block ----
        float* sW1 = (float*)smem;
        for (int i = tid; i < D * D; i += HTH) sW1[i] = W1[i];
        __syncthreads();

        int lane = tid & 63;
        int wv = __builtin_amdgcn_readfirstlane(tid >> 6);
        int gb = blockIdx.x - hblocks;
        int r0 = (gb * 16 + wv) * 8;
        if (r0 >= n) return;

        float acc[8];
#pragma unroll
        for (int i = 0; i < 8; ++i) acc[i] = 0.0f;

        if (r0 + 8 <= n) {
            const float* xw = x + (size_t)r0 * D;
#pragma unroll
            for (int kt = 0; kt < 8; ++kt) {
                const float* p = xw + kt * 8;
                f32x8 X0, X1, X2, X3, X4, X5, X6, X7;
                asm volatile(
                    "s_load_dwordx8 %0, %8, 0x0\n\t"
                    "s_load_dwordx8 %1, %8, 0x100\n\t"
                    "s_load_dwordx8 %2, %8, 0x200\n\t"
                    "s_load_dwordx8 %3, %8, 0x300\n\t"
                    "s_load_dwordx8 %4, %8, 0x400\n\t"
                    "s_load_dwordx8 %5, %8, 0x500\n\t"
                    "s_load_dwordx8 %6, %8, 0x600\n\t"
                    "s_load_dwordx8 %7, %8, 0x700\n\t"
                    "s_waitcnt lgkmcnt(0)"
                    : "=s"(X0), "=s"(X1), "=s"(X2), "=s"(X3),
                      "=s"(X4), "=s"(X5), "=s"(X6), "=s"(X7)
                    : "s"(p));
#pragma unroll
                for (int j = 0; j < 8; ++j) {
                    float wk = sW1[(kt * 8 + j) * D + lane];
                    acc[0] = fmaf(X0[j], wk, acc[0]);
                    acc[1] = fmaf(X1[j], wk, acc[1]);
                    acc[2] = fmaf(X2[j], wk, acc[2]);
                    acc[3] = fmaf(X3[j], wk, acc[3]);
                    acc[4] = fmaf(X4[j], wk, acc[4]);
                    acc[5] = fmaf(X5[j], wk, acc[5]);
                    acc[6] = fmaf(X6[j], wk, acc[6]);
                    acc[7] = fmaf(X7[j], wk, acc[7]);
                }
            }
#pragma unroll
            for (int i = 0; i < 8; ++i)
                y[(size_t)(r0 + i) * D + lane] = acc[i];
        } else {
            // tail (never taken for n % 8 == 0)
            float xr[8];
#pragma unroll
            for (int i = 0; i < 8; ++i) {
                int r = r0 + i;
                xr[i] = (r < n) ? x[(size_t)r * D + lane] : 0.0f;
            }
#pragma unroll
            for (int k = 0; k < D; ++k) {
                float wk = sW1[k * D + lane];
#pragma unroll
                for (int i = 0; i < 8; ++i)
                    acc[i] = fmaf(rl_f(xr[i], k), wk, acc[i]);
            }
#pragma unroll
            for (int i = 0; i < 8; ++i) {
                int r = r0 + i;
                if (r < n) y[(size_t)r * D + lane] = acc[i];
            }
        }
    }
}

// per node: sum 64 partials -> counts + colpref; then block-local exclusive
// scan of cnt_in -> cursor(partial) + per-block sum
__global__ void k_merge_scan(const unsigned int* __restrict__ part,
                             unsigned short* __restrict__ colpref,
                             int* __restrict__ cnt_out, int* __restrict__ cnt_in,
                             int* __restrict__ cursor, int* __restrict__ bsum, int n) {
    __shared__ int s[256];
    int tid = threadIdx.x;
    int v = blockIdx.x * 256 + tid;
    int ci = 0;
    if (v < n) {
        int pass = v / NODE_TILE;
        int vl = v - pass * NODE_TILE;
        const unsigned int* p = part + (size_t)pass * NCHUNK * NODE_TILE + vl;
        unsigned int tot = 0, run_in = 0;
        for (int b = 0; b < NCHUNK; ++b) {
            colpref[(size_t)b * n + v] = (unsigned short)run_in;
            unsigned int t = p[(size_t)b * NODE_TILE];
            tot += t;
            run_in += t >> 16;
        }
        cnt_out[v] = (int)(tot & 0xFFFFu);
        ci = (int)(tot >> 16);
        cnt_in[v] = ci;
    }
    s[tid] = ci;
    __syncthreads();
#pragma unroll
    for (int off = 1; off < 256; off <<= 1) {
        int t = (tid >= off) ? s[tid - off] : 0;
        __syncthreads();
        s[tid] += t;
        __syncthreads();
    }
    if (v < n) cursor[v] = s[tid] - ci;
    if (tid == 255) bsum[blockIdx.x] = s[255];
}

__global__ void k_scan_bsum(int* __restrict__ bsum, int nb) {
    __shared__ int s[256];
    __shared__ int carry;
    int tid = threadIdx.x;
    if (tid == 0) carry = 0;
    __syncthreads();
    for (int start = 0; start < nb; start += 256) {
        int i = start + tid;
        int v = (i < nb) ? bsum[i] : 0;
        s[tid] = v;
        __syncthreads();
#pragma unroll
        for (int off = 1; off < 256; off <<= 1) {
            int t = (tid >= off) ? s[tid - off] : 0;
            __syncthreads();
            s[tid] += t;
            __syncthreads();
        }
        if (i < nb) bsum[i] = s[tid] - v + carry;
        __syncthreads();
        if (tid == 0) carry += s[255];
        __syncthreads();
    }
}

// bin via LDS cursor; computes global start inline (cursor + bsum);
// b==0 blocks also emit meta[v] = (start, cnt_in, cnt_out, 0)
__global__ void __launch_bounds__(HTH) k_bin_lds(
        const int* __restrict__ src, const int* __restrict__ dst,
        const int* __restrict__ cursor, const int* __restrict__ bsum,
        const unsigned short* __restrict__ colpref,
        const int* __restrict__ cnt_out, const int* __restrict__ cnt_in,
        unsigned int* __restrict__ col, int4* __restrict__ meta,
        int e, int n, int ce) {
    __shared__ int cur[NODE_TILE];
    int b = blockIdx.x;
    int v0 = blockIdx.y * NODE_TILE;
    int vcnt = min(NODE_TILE, n - v0);
    for (int i = threadIdx.x; i < vcnt; i += HTH) {
        int v = v0 + i;
        int gs = cursor[v] + bsum[v >> 8];
        cur[i] = gs + (int)colpref[(size_t)b * n + v];
        if (b == 0) meta[v] = make_int4(gs, cnt_in[v], cnt_out[v], 0);
    }
    __syncthreads();
    int lo = b * ce, hi = min(lo + ce, e);
    for (int i = lo + threadIdx.x; i < hi; i += HTH) {
        int d = dst[i];
        unsigned int ud = (unsigned int)(d - v0);
        if (ud < (unsigned int)NODE_TILE) {
            int s = src[i];
            int p = atomicAdd(&cur[ud], 1);
            col[p] = (unsigned int)s | ((unsigned int)cnt_out[s] << 16);
        }
    }
}

// one wave per node (grid-stride); all loads coalesced; col unpacked per-lane
__global__ void __launch_bounds__(256) k_node(
        const float* __restrict__ y, const int4* __restrict__ meta,
        const unsigned int* __restrict__ col,
        const float* __restrict__ b1, const float* __restrict__ W2,
        float* __restrict__ zs, int n) {
    int tid = threadIdx.x;
    int wave = tid >> 6;
    int lane = tid & 63;
    float b1v = b1[lane];
    float w2v = W2[lane];

    int nwaves = gridDim.x * 4;
    int node = blockIdx.x * 4 + wave;
    if (node >= n) return;
    int4 mt = meta[node];

    while (true) {
        int nxt = node + nwaves;
        int4 mt_nx = make_int4(0, 0, 0, 0);
        if (nxt < n) mt_nx = meta[nxt];          // prefetch next node's meta

        int base = mt.x;
        int cnt = mt.y;
        float nd = rsqrtf((float)(mt.y + 1));    // norm_dst
        float ns = rsqrtf((float)(mt.z + 1));    // norm_src

        float a0 = ns * y[(size_t)node * D + lane];  // self loop
        float a1 = 0.0f, a2 = 0.0f, a3 = 0.0f;

        for (int b0 = 0; b0 < cnt; b0 += 64) {
            int m = cnt - b0; if (m > 64) m = 64;
            unsigned int cw = (lane < m) ? col[base + b0 + lane] : 0u;
            int idx = (int)(cw & 0xFFFFu);
            float w = rsqrtf((float)(cw >> 16) + 1.0f);  // norm_src[idx]
            int j = 0;
            for (; j + 8 <= m; j += 8) {
                int s0 = rl_i(idx, j + 0), s1 = rl_i(idx, j + 1);
                int s2 = rl_i(idx, j + 2), s3 = rl_i(idx, j + 3);
                int s4 = rl_i(idx, j + 4), s5 = rl_i(idx, j + 5);
                int s6 = rl_i(idx, j + 6), s7 = rl_i(idx, j + 7);
                float x0 = y[(size_t)s0 * D + lane];
                float x1 = y[(size_t)s1 * D + lane];
                float x2 = y[(size_t)s2 * D + lane];
                float x3 = y[(size_t)s3 * D + lane];
                float x4 = y[(size_t)s4 * D + lane];
                float x5 = y[(size_t)s5 * D + lane];
                float x6 = y[(size_t)s6 * D + lane];
                float x7 = y[(size_t)s7 * D + lane];
                a0 = fmaf(rl_f(w, j + 0), x0, a0);
                a1 = fmaf(rl_f(w, j + 1), x1, a1);
                a2 = fmaf(rl_f(w, j + 2), x2, a2);
                a3 = fmaf(rl_f(w, j + 3), x3, a3);
                a0 = fmaf(rl_f(w, j + 4), x4, a0);
                a1 = fmaf(rl_f(w, j + 5), x5, a1);
                a2 = fmaf(rl_f(w, j + 6), x6, a2);
                a3 = fmaf(rl_f(w, j + 7), x7, a3);
            }
            for (; j < m; ++j)
                a0 = fmaf(rl_f(w, j), y[(size_t)rl_i(idx, j) * D + lane], a0);
        }

        float h = fmaxf(((a0 + a1) + (a2 + a3)) * nd + b1v, 0.0f);
        float zp = h * w2v;
#pragma unroll
        for (int off = 32; off > 0; off >>= 1) zp += __shfl_down(zp, off);
        if (lane == 0) zs[node] = zp * ns;       // pre-scaled for layer 2

        if (nxt >= n) break;
        node = nxt;
        mt = mt_nx;
    }
}

// layer-2 gather: 8 lanes per node
__global__ void k_out(const float* __restrict__ zs,
                      const int4* __restrict__ meta, const unsigned int* __restrict__ col,
                      const float* __restrict__ b2,
                      float* __restrict__ out, int n) {
    int g = blockIdx.x * blockDim.x + threadIdx.x;
    int node = g >> 3;
    int sub = g & 7;
    if (node >= n) return;
    int4 mt = meta[node];
    int base = mt.x;
    int c = mt.y;
    float s = (sub == 0) ? zs[node] : 0.0f;   // self loop (zs pre-scaled)
    for (int j = sub; j < c; j += 8) s += zs[col[base + j] & 0xFFFFu];
    s += __shfl_xor(s, 1);
    s += __shfl_xor(s, 2);
    s += __shfl_xor(s, 4);
    if (sub == 0) {
        float nd = rsqrtf((float)(mt.y + 1));
        out[node] = nd * s + b2[0];
    }
}

extern "C" void kernel_launch(void* const* d_in, const int* in_sizes, int n_in,
                              void* d_out, int out_size, void* d_ws, size_t ws_size,
                              hipStream_t stream) {
    const float* x  = (const float*)d_in[0];
    const int*   ei = (const int*)d_in[1];
    const float* W1 = (const float*)d_in[2];
    const float* b1 = (const float*)d_in[3];
    const float* W2 = (const float*)d_in[4];
    const float* b2 = (const float*)d_in[5];
    float* out = (float*)d_out;

    const int n = in_sizes[0] / D;   // 50000
    const int e = in_sizes[1] / 2;   // 800000
    const int* src = ei;
    const int* dst = ei + e;

    const int nb = (n + 255) / 256;
    const int npass = (n + NODE_TILE - 1) / NODE_TILE;      // 4
    const int ce = (e + NCHUNK - 1) / NCHUNK;               // 12500
    const int hblocks = NCHUNK * npass;                     // 256
    const int gblocks = (n + 127) / 128;                    // 391

    // workspace layout -- no overlays (ws >= 268 MB)
    char* ws = (char*)d_ws;
    int*   cnt_out = (int*)ws;   ws += sizeof(int) * (size_t)n;
    int*   cnt_in  = (int*)ws;   ws += sizeof(int) * (size_t)n;
    int*   cursor  = (int*)ws;   ws += sizeof(int) * (size_t)n;
    int*   bsum    = (int*)ws;   ws += sizeof(int) * (size_t)((nb + 255) & ~255);
    int4*  meta    = (int4*)ws;  ws += sizeof(int4) * (size_t)n;
    unsigned short* colpref = (unsigned short*)ws;
    ws += sizeof(unsigned short) * (size_t)NCHUNK * n;
    unsigned int* col = (unsigned int*)ws;  ws += sizeof(unsigned int) * (size_t)e;
    unsigned int* part = (unsigned int*)ws;
    ws += sizeof(unsigned int) * (size_t)npass * NCHUNK * NODE_TILE;
    float* y  = (float*)ws;      ws += sizeof(float) * (size_t)n * D;
    float* zs = (float*)ws;      ws += sizeof(float) * (size_t)n;

    const int B = 256;
    const size_t smem = (size_t)NODE_TILE * sizeof(unsigned int);  // 50 KB

    k_hist_gemm<<<hblocks + gblocks, HTH, smem, stream>>>(
        src, dst, part, e, ce, hblocks, x, W1, y, n);
    k_merge_scan<<<nb, 256, 0, stream>>>(part, colpref, cnt_out, cnt_in, cursor, bsum, n);
    k_scan_bsum<<<1, 256, 0, stream>>>(bsum, nb);
    k_bin_lds<<<dim3(NCHUNK, npass), HTH, 0, stream>>>(
        src, dst, cursor, bsum, colpref, cnt_out, cnt_in, col, meta, e, n, ce);
    k_node<<<2048, B, 0, stream>>>(y, meta, col, b1, W2, zs, n);
    k_out<<<((size_t)n * 8 + B - 1) / B, B, 0, stream>>>(zs, meta, col, b2, out, n);
}